// Round 1
// baseline (1179.317 us; speedup 1.0000x reference)
//
#include <hip/hip_runtime.h>
#include <math.h>

#define NE   8192      // codes
#define ED   512       // embedding dim
#define BB   8         // batch
#define TT   1024      // time
#define MM   (BB*TT)   // 8192 z-rows
#define KC   64        // k-chunk
#define LDSP 68        // padded LDS row stride (floats), 16B-aligned rows

#define FLT_BIG 3.402823466e38f

// ---------------------------------------------------------------------------
// K1: codebook[n][d] = sum_k emb[n][k]*pw[d][k] + pb[d];  cnorm[n] = ||row||^2
// NT GEMM, 64x64 tile, 256 threads, 4x4 acc/thread.
// ---------------------------------------------------------------------------
__global__ __launch_bounds__(256) void k_codebook(
    const float* __restrict__ emb, const float* __restrict__ pw,
    const float* __restrict__ pb, float* __restrict__ cb,
    float* __restrict__ cnorm)
{
    __shared__ float As[KC][LDSP];   // [k][n_local]
    __shared__ float Bs[KC][LDSP];   // [k][d_local]
    const int tid = threadIdx.x;
    const int tx = tid & 15, ty = tid >> 4;
    const int n0 = blockIdx.x * 64;
    const int d0 = blockIdx.y * 64;

    float acc[4][4] = {};

    for (int kc = 0; kc < ED; kc += KC) {
        const int k4 = tid & 15;            // float4 index along k
#pragma unroll
        for (int r = 0; r < 4; ++r) {
            const int row = (tid >> 4) + r * 16;
            const float4 a = *(const float4*)(emb + (size_t)(n0 + row) * ED + kc + k4 * 4);
            As[k4*4+0][row] = a.x; As[k4*4+1][row] = a.y;
            As[k4*4+2][row] = a.z; As[k4*4+3][row] = a.w;
            const float4 w = *(const float4*)(pw + (size_t)(d0 + row) * ED + kc + k4 * 4);
            Bs[k4*4+0][row] = w.x; Bs[k4*4+1][row] = w.y;
            Bs[k4*4+2][row] = w.z; Bs[k4*4+3][row] = w.w;
        }
        __syncthreads();
#pragma unroll 16
        for (int kk = 0; kk < KC; ++kk) {
            const float4 a = *(const float4*)&As[kk][ty*4];
            const float4 b = *(const float4*)&Bs[kk][tx*4];
            acc[0][0] += a.x*b.x; acc[0][1] += a.x*b.y; acc[0][2] += a.x*b.z; acc[0][3] += a.x*b.w;
            acc[1][0] += a.y*b.x; acc[1][1] += a.y*b.y; acc[1][2] += a.y*b.z; acc[1][3] += a.y*b.w;
            acc[2][0] += a.z*b.x; acc[2][1] += a.z*b.y; acc[2][2] += a.z*b.z; acc[2][3] += a.z*b.w;
            acc[3][0] += a.w*b.x; acc[3][1] += a.w*b.y; acc[3][2] += a.w*b.z; acc[3][3] += a.w*b.w;
        }
        __syncthreads();
    }

    float bias[4];
#pragma unroll
    for (int j = 0; j < 4; ++j) bias[j] = pb[d0 + tx*4 + j];

    float nsum[4];
#pragma unroll
    for (int i = 0; i < 4; ++i) {
        float4 v;
        v.x = acc[i][0] + bias[0];
        v.y = acc[i][1] + bias[1];
        v.z = acc[i][2] + bias[2];
        v.w = acc[i][3] + bias[3];
        const int n = n0 + ty*4 + i;
        *(float4*)(cb + (size_t)n * ED + d0 + tx*4) = v;
        nsum[i] = v.x*v.x + v.y*v.y + v.z*v.z + v.w*v.w;
    }
    // reduce squared-norm partial across the 16 tx lanes (same ty group)
#pragma unroll
    for (int off = 1; off < 16; off <<= 1) {
#pragma unroll
        for (int i = 0; i < 4; ++i) nsum[i] += __shfl_xor(nsum[i], off);
    }
    if (tx == 0) {
#pragma unroll
        for (int i = 0; i < 4; ++i) atomicAdd(&cnorm[n0 + ty*4 + i], nsum[i]);
    }
}

// ---------------------------------------------------------------------------
// K2: scores f[m][n] = cnorm[n] - 2 * dot(z_row m, cb_row n); running argmin
// over an n-strip of 1024 codes. Grid: (128 m-tiles, 8 strips). Invalid
// strips (domain mask) exit immediately.
// ---------------------------------------------------------------------------
__device__ __forceinline__ bool strip_valid(int dom, int s) {
    return (dom == 3) || (dom == 0 && s < 2) ||
           (dom == 1 && s >= 2 && s < 4) || (dom == 2 && s >= 4);
}

__global__ __launch_bounds__(256) void k_scores(
    const float* __restrict__ z, const int* __restrict__ dom_arr,
    const float* __restrict__ cb, const float* __restrict__ cnorm,
    float* __restrict__ pmin, int* __restrict__ pidx)
{
    const int mt = blockIdx.x;       // 0..127
    const int s  = blockIdx.y;       // 0..7
    const int b  = mt >> 4;          // 16 m-tiles per batch (T/64)
    const int dom = dom_arr[b];
    if (!strip_valid(dom, s)) return;

    __shared__ float Zs[KC][LDSP];   // [k][m_local]  (m_local == t offset)
    __shared__ float Cs[KC][LDSP];   // [k][n_local]
    const int tid = threadIdx.x;
    const int tx = tid & 15, ty = tid >> 4;
    const int m0 = mt * 64;
    const int t0 = (mt & 15) * 64;

    float bestv[4] = {FLT_BIG, FLT_BIG, FLT_BIG, FLT_BIG};
    int   besti[4] = {0, 0, 0, 0};

    for (int nt = 0; nt < 16; ++nt) {
        const int n0 = s * 1024 + nt * 64;
        float acc[4][4] = {};

        for (int kc = 0; kc < ED; kc += KC) {
            {   // stage z: memory is t-contiguous -> direct [c][t] layout
                const int m4 = tid & 15;
#pragma unroll
                for (int r = 0; r < 4; ++r) {
                    const int cl = (tid >> 4) + r * 16;
                    const float4 v = *(const float4*)(z + ((size_t)(b * ED + kc + cl)) * TT + t0 + m4 * 4);
                    *(float4*)&Zs[cl][m4*4] = v;
                }
            }
            {   // stage cb rows (k-contiguous) transposed into [k][n]
                const int k4 = tid & 15;
#pragma unroll
                for (int r = 0; r < 4; ++r) {
                    const int row = (tid >> 4) + r * 16;
                    const float4 v = *(const float4*)(cb + (size_t)(n0 + row) * ED + kc + k4 * 4);
                    Cs[k4*4+0][row] = v.x; Cs[k4*4+1][row] = v.y;
                    Cs[k4*4+2][row] = v.z; Cs[k4*4+3][row] = v.w;
                }
            }
            __syncthreads();
#pragma unroll 16
            for (int kk = 0; kk < KC; ++kk) {
                const float4 a = *(const float4*)&Zs[kk][ty*4];
                const float4 c = *(const float4*)&Cs[kk][tx*4];
                acc[0][0] += a.x*c.x; acc[0][1] += a.x*c.y; acc[0][2] += a.x*c.z; acc[0][3] += a.x*c.w;
                acc[1][0] += a.y*c.x; acc[1][1] += a.y*c.y; acc[1][2] += a.y*c.z; acc[1][3] += a.y*c.w;
                acc[2][0] += a.z*c.x; acc[2][1] += a.z*c.y; acc[2][2] += a.z*c.z; acc[2][3] += a.z*c.w;
                acc[3][0] += a.w*c.x; acc[3][1] += a.w*c.y; acc[3][2] += a.w*c.z; acc[3][3] += a.w*c.w;
            }
            __syncthreads();
        }

        // epilogue: f = cnorm - 2*dot ; running per-row argmin (ascending n ->
        // strict < keeps the first/lowest index, matching jnp.argmin)
#pragma unroll
        for (int j = 0; j < 4; ++j) {
            const int n = n0 + tx*4 + j;
            const float cn = cnorm[n];
#pragma unroll
            for (int i = 0; i < 4; ++i) {
                const float f = cn - 2.0f * acc[i][j];
                if (f < bestv[i]) { bestv[i] = f; besti[i] = n; }
            }
        }
    }

    // reduce (val,idx) across the 16 tx lanes; tie -> smaller index
#pragma unroll
    for (int off = 1; off < 16; off <<= 1) {
#pragma unroll
        for (int i = 0; i < 4; ++i) {
            const float ov = __shfl_xor(bestv[i], off);
            const int   oi = __shfl_xor(besti[i], off);
            if (ov < bestv[i] || (ov == bestv[i] && oi < besti[i])) {
                bestv[i] = ov; besti[i] = oi;
            }
        }
    }
    if (tx == 0) {
#pragma unroll
        for (int i = 0; i < 4; ++i) {
            const int m = m0 + ty*4 + i;
            pmin[m*8 + s] = bestv[i];
            pidx[m*8 + s] = besti[i];
        }
    }
}

// ---------------------------------------------------------------------------
// P2: reduce the (up to 8) strip partials per row -> final index; write the
// float-encoded min_idx output.
// ---------------------------------------------------------------------------
__global__ __launch_bounds__(256) void k_reduce(
    const float* __restrict__ pmin, const int* __restrict__ pidx,
    const int* __restrict__ dom_arr, int* __restrict__ minidx,
    float* __restrict__ out_idx)
{
    const int m = blockIdx.x * 256 + threadIdx.x;  // 0..8191
    const int b = m >> 10;
    const int dom = dom_arr[b];
    float bv = FLT_BIG; int bi = 0;
    for (int s = 0; s < 8; ++s) {
        if (!strip_valid(dom, s)) continue;
        const float v = pmin[m*8 + s];
        const int   i = pidx[m*8 + s];
        if (v < bv) { bv = v; bi = i; }   // ascending s == ascending n
    }
    minidx[m] = bi;
    out_idx[m] = (float)bi;
}

// ---------------------------------------------------------------------------
// P3: z_q gather + transpose to (B,C,T) + commit-loss partial accumulation.
// One block per (b, 64-t tile). t is lane-contiguous -> coalesced z read and
// z_q write; cb access is a gather (L1/L2-cached rows).
// ---------------------------------------------------------------------------
__global__ __launch_bounds__(256) void k_zq(
    const float* __restrict__ z, const float* __restrict__ cb,
    const int* __restrict__ minidx, float* __restrict__ outz,
    float* __restrict__ lossacc)
{
    __shared__ float red[4];
    const int blk = blockIdx.x;          // 0..127
    const int b = blk >> 4;
    const int t0 = (blk & 15) * 64;
    const int tl = threadIdx.x & 63;
    const int cg = threadIdx.x >> 6;     // 0..3
    const int t = t0 + tl;
    const int idx = minidx[b * TT + t];
    const float* __restrict__ crow = cb + (size_t)idx * ED;

    float lsum = 0.f;
    for (int c = cg; c < ED; c += 4) {
        const float cv = crow[c];
        const size_t off = ((size_t)(b * ED + c)) * TT + t;
        const float zv = z[off];
        const float d = cv - zv;
        lsum += d * d;
        outz[off] = cv;
    }
    // wave reduce (64 lanes) then cross-wave via LDS
#pragma unroll
    for (int off = 32; off > 0; off >>= 1) lsum += __shfl_down(lsum, off);
    if (tl == 0) red[threadIdx.x >> 6] = lsum;
    __syncthreads();
    if (threadIdx.x == 0)
        atomicAdd(lossacc, red[0] + red[1] + red[2] + red[3]);
}

__global__ void k_final(const float* __restrict__ lossacc, float* __restrict__ outloss)
{
    *outloss = 1.25f * (*lossacc) / (float)(BB * ED * TT);
}

// ---------------------------------------------------------------------------
extern "C" void kernel_launch(void* const* d_in, const int* in_sizes, int n_in,
                              void* d_out, int out_size, void* d_ws, size_t ws_size,
                              hipStream_t stream)
{
    const float* z   = (const float*)d_in[0];
    const int*   dom = (const int*)d_in[1];
    // d_in[2] = n_q (unused, always 1)
    const float* emb = (const float*)d_in[3];
    const float* pw  = (const float*)d_in[4];
    const float* pb  = (const float*)d_in[5];
    float* out = (float*)d_out;

    // workspace layout (floats)
    float* ws      = (float*)d_ws;
    float* cb      = ws;                          // 8192*512
    float* cnorm   = cb + (size_t)NE * ED;        // 8192
    float* pmin    = cnorm + NE;                  // 8192*8
    int*   pidx    = (int*)(pmin + MM * 8);       // 8192*8
    int*   minidx  = pidx + MM * 8;               // 8192
    float* lossacc = (float*)(minidx + MM);       // 1

    hipMemsetAsync(cnorm, 0, NE * sizeof(float), stream);
    hipMemsetAsync(lossacc, 0, sizeof(float), stream);

    k_codebook<<<dim3(128, 8), 256, 0, stream>>>(emb, pw, pb, cb, cnorm);
    k_scores  <<<dim3(128, 8), 256, 0, stream>>>(z, dom, cb, cnorm, pmin, pidx);
    k_reduce  <<<32, 256, 0, stream>>>(pmin, pidx, dom, minidx, out + (size_t)NE * ED);
    k_zq      <<<128, 256, 0, stream>>>(z, cb, minidx, out, lossacc);
    k_final   <<<1, 1, 0, stream>>>(lossacc, out + (size_t)NE * ED + MM);
}

// Round 2
// 423.494 us; speedup vs baseline: 2.7847x; 2.7847x over previous
//
#include <hip/hip_runtime.h>
#include <math.h>

#define NE   8192
#define ED   512
#define BB   8
#define TT   1024
#define MM   (BB*TT)
#define KC   64
#define LDSP 68

typedef _Float16 half8 __attribute__((ext_vector_type(8)));
typedef _Float16 half4 __attribute__((ext_vector_type(4)));
typedef float    floatx4 __attribute__((ext_vector_type(4)));

typedef __attribute__((address_space(3))) unsigned int       lds_u32;
typedef const __attribute__((address_space(1))) unsigned int gbl_u32;

// async global->LDS, 16B per lane; LDS dest = wave-uniform base + lane*16
__device__ __forceinline__ void async_copy16(void* lds, const void* g) {
    __builtin_amdgcn_global_load_lds((gbl_u32*)(unsigned long long)g,
                                     (lds_u32*)(unsigned long long)lds,
                                     16, 0, 0);
}

// ---------------------------------------------------------------------------
// K0: z (B,C,T) fp32 -> Zb[m][0:512]=f16(4z) hi, Zb[m][512:1024]=f16 residual
// (m = b*T + t, k-contiguous rows for GEMM staging). 64x64 transpose tiles.
// ---------------------------------------------------------------------------
__global__ __launch_bounds__(256) void k_prep_z(
    const float* __restrict__ z, _Float16* __restrict__ Zb)
{
    __shared__ float T[64][65];
    const int ct = blockIdx.x, tt = blockIdx.y, b = blockIdx.z;
    const int tid = threadIdx.x;
    const int f4 = tid & 15;     // float4 index along t
    const int c0 = tid >> 4;     // 0..15
#pragma unroll
    for (int r = 0; r < 4; ++r) {
        const int c = c0 + r * 16;
        const float4 v = *(const float4*)(z + ((size_t)(b * ED + ct * 64 + c)) * TT + tt * 64 + f4 * 4);
        T[f4*4+0][c] = v.x; T[f4*4+1][c] = v.y;
        T[f4*4+2][c] = v.z; T[f4*4+3][c] = v.w;
    }
    __syncthreads();
    const int tl = tid >> 2, q = tid & 3;
    const size_t m = (size_t)b * TT + tt * 64 + tl;
    _Float16* outh = Zb + m * 1024 + ct * 64 + q * 16;
#pragma unroll
    for (int g = 0; g < 2; ++g) {
        half8 hv, lv;
#pragma unroll
        for (int jj = 0; jj < 8; ++jj) {
            const float v = 4.0f * T[tl][q*16 + g*8 + jj];
            const _Float16 h = (_Float16)v;
            hv[jj] = h;
            lv[jj] = (_Float16)(v - (float)h);
        }
        *(half8*)(outh + g * 8) = hv;
        *(half8*)(outh + 512 + g * 8) = lv;
    }
}

// ---------------------------------------------------------------------------
// K1: codebook = emb @ pw^T + pb (fp32), emit f16 hi/lo at 64x scale into
// Cb[n][0:512 | 512:1024], plus exact fp32 row norms (atomic partials).
// ---------------------------------------------------------------------------
__global__ __launch_bounds__(256) void k_codebook(
    const float* __restrict__ emb, const float* __restrict__ pw,
    const float* __restrict__ pb, _Float16* __restrict__ Cb,
    float* __restrict__ cnorm)
{
    __shared__ float As[KC][LDSP];
    __shared__ float Bs[KC][LDSP];
    const int tid = threadIdx.x;
    const int tx = tid & 15, ty = tid >> 4;
    const int n0 = blockIdx.x * 64;
    const int d0 = blockIdx.y * 64;

    float acc[4][4] = {};

    for (int kc = 0; kc < ED; kc += KC) {
        const int k4 = tid & 15;
#pragma unroll
        for (int r = 0; r < 4; ++r) {
            const int row = (tid >> 4) + r * 16;
            const float4 a = *(const float4*)(emb + (size_t)(n0 + row) * ED + kc + k4 * 4);
            As[k4*4+0][row] = a.x; As[k4*4+1][row] = a.y;
            As[k4*4+2][row] = a.z; As[k4*4+3][row] = a.w;
            const float4 w = *(const float4*)(pw + (size_t)(d0 + row) * ED + kc + k4 * 4);
            Bs[k4*4+0][row] = w.x; Bs[k4*4+1][row] = w.y;
            Bs[k4*4+2][row] = w.z; Bs[k4*4+3][row] = w.w;
        }
        __syncthreads();
#pragma unroll 16
        for (int kk = 0; kk < KC; ++kk) {
            const float4 a = *(const float4*)&As[kk][ty*4];
            const float4 b = *(const float4*)&Bs[kk][tx*4];
            acc[0][0] += a.x*b.x; acc[0][1] += a.x*b.y; acc[0][2] += a.x*b.z; acc[0][3] += a.x*b.w;
            acc[1][0] += a.y*b.x; acc[1][1] += a.y*b.y; acc[1][2] += a.y*b.z; acc[1][3] += a.y*b.w;
            acc[2][0] += a.z*b.x; acc[2][1] += a.z*b.y; acc[2][2] += a.z*b.z; acc[2][3] += a.z*b.w;
            acc[3][0] += a.w*b.x; acc[3][1] += a.w*b.y; acc[3][2] += a.w*b.z; acc[3][3] += a.w*b.w;
        }
        __syncthreads();
    }

    float bias[4];
#pragma unroll
    for (int j = 0; j < 4; ++j) bias[j] = pb[d0 + tx*4 + j];

    float nsum[4];
#pragma unroll
    for (int i = 0; i < 4; ++i) {
        float v[4];
#pragma unroll
        for (int j = 0; j < 4; ++j) v[j] = acc[i][j] + bias[j];
        const int n = n0 + ty*4 + i;
        half4 hv, lv;
#pragma unroll
        for (int j = 0; j < 4; ++j) {
            const float av = v[j] * 64.0f;
            const _Float16 h = (_Float16)av;
            hv[j] = h;
            lv[j] = (_Float16)(av - (float)h);
        }
        *(half4*)(Cb + (size_t)n * 1024 + d0 + tx*4) = hv;
        *(half4*)(Cb + (size_t)n * 1024 + 512 + d0 + tx*4) = lv;
        nsum[i] = v[0]*v[0] + v[1]*v[1] + v[2]*v[2] + v[3]*v[3];
    }
#pragma unroll
    for (int off = 1; off < 16; off <<= 1) {
#pragma unroll
        for (int i = 0; i < 4; ++i) nsum[i] += __shfl_xor(nsum[i], off);
    }
    if (tx == 0) {
#pragma unroll
        for (int i = 0; i < 4; ++i) atomicAdd(&cnorm[n0 + ty*4 + i], nsum[i]);
    }
}

// ---------------------------------------------------------------------------
// K2: MFMA distance GEMM. logical K=1536 = [zh,zh,zl] x [ch,cl,ch] over the
// K=1024 stored splits. 128x128 block tile, 4 waves of 64x64 (4x4 of
// 16x16x32 f16 MFMA). Argmin merged globally via packed u64 atomicMin.
// ---------------------------------------------------------------------------
__global__ __launch_bounds__(256) void k_scores(
    const _Float16* __restrict__ Zb, const _Float16* __restrict__ Cb,
    const float* __restrict__ cnorm, const int* __restrict__ dom_arr,
    unsigned long long* __restrict__ minrec)
{
    const int mt = blockIdx.x;          // 0..63
    const int nt = blockIdx.y;          // 0..63
    const int b = mt >> 3;
    const int dom = dom_arr[b];
    const int chunk = nt >> 4;          // 2048-code domain chunks
    const bool valid = (dom == 3) || (dom == 0 && chunk == 0) ||
                       (dom == 1 && chunk == 1) || (dom == 2 && chunk >= 2);
    if (!valid) return;

    __shared__ __align__(16) _Float16 As[128 * 64];
    __shared__ __align__(16) _Float16 Bs[128 * 64];

    const int tid = threadIdx.x;
    const int wave = tid >> 6, lane = tid & 63;
    const int m0 = mt * 128, n0 = nt * 128;
    const int wm = wave >> 1, wn = wave & 1;
    const int lm = lane & 15, lq = lane >> 4;

    floatx4 acc[4][4];
#pragma unroll
    for (int i = 0; i < 4; ++i)
#pragma unroll
        for (int j = 0; j < 4; ++j) acc[i][j] = (floatx4)0.0f;

    for (int lc = 0; lc < 24; ++lc) {
        const int kA = (lc < 8) ? lc * 64 : (lc < 16 ? (lc - 8) * 64 : 512 + (lc - 16) * 64);
        const int kB = (lc < 8) ? lc * 64 : (lc < 16 ? 512 + (lc - 8) * 64 : (lc - 16) * 64);

        __syncthreads();   // previous iteration's LDS reads complete
#pragma unroll
        for (int r = 0; r < 4; ++r) {
            const int s = wave * 4 + r;            // 1KB span = 8 rows
            const int row = s * 8 + (lane >> 3);
            const int src = (lane & 7) ^ (row & 7);   // XOR chunk swizzle
            async_copy16(&As[s * 512], Zb + (size_t)(m0 + row) * 1024 + kA + src * 8);
            async_copy16(&Bs[s * 512], Cb + (size_t)(n0 + row) * 1024 + kB + src * 8);
        }
        __syncthreads();   // drains vmcnt (global_load_lds) per compiler barrier rule

#pragma unroll
        for (int ks = 0; ks < 2; ++ks) {
            half8 af[4], bf[4];
#pragma unroll
            for (int i = 0; i < 4; ++i) {
                const int row = wm * 64 + i * 16 + lm;
                const int slot = (ks * 4 + lq) ^ (row & 7);
                af[i] = *(const half8*)&As[row * 64 + slot * 8];
            }
#pragma unroll
            for (int j = 0; j < 4; ++j) {
                const int row = wn * 64 + j * 16 + lm;
                const int slot = (ks * 4 + lq) ^ (row & 7);
                bf[j] = *(const half8*)&Bs[row * 64 + slot * 8];
            }
#pragma unroll
            for (int i = 0; i < 4; ++i)
#pragma unroll
                for (int j = 0; j < 4; ++j)
                    acc[i][j] = __builtin_amdgcn_mfma_f32_16x16x32_f16(af[i], bf[j], acc[i][j], 0, 0, 0);
        }
    }

    // epilogue: f = cnorm[n] - acc/128 ; per-row argmin packed (fkey<<32|n)
    unsigned long long key[16];
#pragma unroll
    for (int p = 0; p < 16; ++p) key[p] = ~0ull;

#pragma unroll
    for (int j = 0; j < 4; ++j) {
        const int n = n0 + wn * 64 + j * 16 + lm;
        const float cn = cnorm[n];
#pragma unroll
        for (int i = 0; i < 4; ++i) {
#pragma unroll
            for (int r = 0; r < 4; ++r) {
                const float f = cn - acc[i][j][r] * 0.0078125f;
                unsigned int u = __float_as_uint(f);
                u = (u & 0x80000000u) ? ~u : (u | 0x80000000u);
                const unsigned long long k = ((unsigned long long)u << 32) | (unsigned int)n;
                if (k < key[i*4+r]) key[i*4+r] = k;
            }
        }
    }
    // reduce across the 16 cols held by lanes lm=0..15 (same lq group)
#pragma unroll
    for (int stp = 1; stp < 16; stp <<= 1) {
#pragma unroll
        for (int p = 0; p < 16; ++p) {
            const unsigned long long o = __shfl_xor(key[p], stp);
            if (o < key[p]) key[p] = o;
        }
    }
    // lane lm handles pair p=lm: m = m0 + wm*64 + (p>>2)*16 + lq*4 + (p&3)
    unsigned long long mykey = key[0];
#pragma unroll
    for (int p = 1; p < 16; ++p) if (lm == p) mykey = key[p];
    const int m = m0 + wm * 64 + (lm >> 2) * 16 + lq * 4 + (lm & 3);
    atomicMin(&minrec[m], mykey);
}

// ---------------------------------------------------------------------------
// K3: unpack argmin records -> minidx + float-encoded idx output
// ---------------------------------------------------------------------------
__global__ __launch_bounds__(256) void k_reduce(
    const unsigned long long* __restrict__ minrec,
    int* __restrict__ minidx, float* __restrict__ out_idx)
{
    const int m = blockIdx.x * 256 + threadIdx.x;
    const int idx = (int)(minrec[m] & 0xFFFFFFFFull);
    minidx[m] = idx;
    out_idx[m] = (float)idx;
}

// ---------------------------------------------------------------------------
// K4: z_q gather (reconstruct fp32 codebook from hi+lo at 1/64 scale),
// transpose to (B,C,T), commit-loss accumulation.
// ---------------------------------------------------------------------------
__global__ __launch_bounds__(256) void k_zq(
    const float* __restrict__ z, const _Float16* __restrict__ Cb,
    const int* __restrict__ minidx, float* __restrict__ outz,
    float* __restrict__ lossacc)
{
    __shared__ float red[4];
    const int blk = blockIdx.x;
    const int b = blk >> 4;
    const int t0 = (blk & 15) * 64;
    const int tl = threadIdx.x & 63;
    const int cg = threadIdx.x >> 6;
    const int t = t0 + tl;
    const int idx = minidx[b * TT + t];
    const _Float16* __restrict__ crow = Cb + (size_t)idx * 1024;

    float lsum = 0.f;
    for (int c = cg; c < ED; c += 4) {
        const float cv = ((float)crow[c] + (float)crow[512 + c]) * 0.015625f;
        const size_t off = ((size_t)(b * ED + c)) * TT + t;
        const float zv = z[off];
        const float d = cv - zv;
        lsum += d * d;
        outz[off] = cv;
    }
#pragma unroll
    for (int off = 32; off > 0; off >>= 1) lsum += __shfl_down(lsum, off);
    if (tl == 0) red[threadIdx.x >> 6] = lsum;
    __syncthreads();
    if (threadIdx.x == 0)
        atomicAdd(lossacc, red[0] + red[1] + red[2] + red[3]);
}

__global__ void k_final(const float* __restrict__ lossacc, float* __restrict__ outloss)
{
    *outloss = 1.25f * (*lossacc) / (float)(BB * ED * TT);
}

// ---------------------------------------------------------------------------
extern "C" void kernel_launch(void* const* d_in, const int* in_sizes, int n_in,
                              void* d_out, int out_size, void* d_ws, size_t ws_size,
                              hipStream_t stream)
{
    const float* z   = (const float*)d_in[0];
    const int*   dom = (const int*)d_in[1];
    const float* emb = (const float*)d_in[3];
    const float* pw  = (const float*)d_in[4];
    const float* pb  = (const float*)d_in[5];
    float* out = (float*)d_out;

    // workspace layout
    _Float16* Zb = (_Float16*)d_ws;                               // 8192*1024 f16
    _Float16* Cb = Zb + (size_t)MM * 1024;                        // 8192*1024 f16
    float* cnorm = (float*)(Cb + (size_t)NE * 1024);              // 8192 f32
    unsigned long long* minrec = (unsigned long long*)(cnorm + NE); // 8192 u64
    int* minidx = (int*)(minrec + MM);                            // 8192 i32
    float* lossacc = (float*)(minidx + MM);                       // 1 f32

    hipMemsetAsync(cnorm, 0, NE * sizeof(float), stream);
    hipMemsetAsync(minrec, 0xFF, MM * sizeof(unsigned long long), stream);
    hipMemsetAsync(lossacc, 0, sizeof(float), stream);

    k_prep_z  <<<dim3(8, 16, 8), 256, 0, stream>>>(z, Zb);
    k_codebook<<<dim3(128, 8), 256, 0, stream>>>(emb, pw, pb, Cb, cnorm);
    k_scores  <<<dim3(64, 64), 256, 0, stream>>>(Zb, Cb, cnorm, dom, minrec);
    k_reduce  <<<32, 256, 0, stream>>>(minrec, minidx, out + (size_t)NE * ED);
    k_zq      <<<128, 256, 0, stream>>>(z, Cb, minidx, out, lossacc);
    k_final   <<<1, 1, 0, stream>>>(lossacc, out + (size_t)NE * ED + MM);
}